// Round 1
// baseline (16219.508 us; speedup 1.0000x reference)
//
#include <hip/hip_runtime.h>
#include <hip/hip_bf16.h>

#define B_ 512
#define T_ 256
#define E_ 512
#define H_ 1024
#define K_ 1536  // E+H

typedef __attribute__((ext_vector_type(4))) float f32x4;
typedef __attribute__((ext_vector_type(8))) short s16x8;

static __device__ __forceinline__ short f2b(float f) {
    union { float f; unsigned u; } v; v.f = f;
    unsigned r = v.u + 0x7FFFu + ((v.u >> 16) & 1u);   // RNE
    return (short)(r >> 16);
}
static __device__ __forceinline__ float sigmoidf_(float v) {
    return 1.f / (1.f + expf(-v));
}

// ---------------------------------------------------------------------------
// prep: W (fp32, [k][n]) -> Wt (bf16, [n][k]); zero h state
// ---------------------------------------------------------------------------
__global__ __launch_bounds__(256) void prep_kernel(
    const float* __restrict__ W_r, const float* __restrict__ W_z,
    const float* __restrict__ W_c,
    short* __restrict__ Wt_rz, short* __restrict__ Wt_c,
    float* __restrict__ hbuf, short* __restrict__ hbf16)
{
    const int PER = H_ * K_;  // 1024*1536
    int idx = blockIdx.x * 256 + threadIdx.x;
    if (idx < PER * 3) {
        int mm = idx / PER, rem = idx - mm * PER;
        int n = rem / K_, k = rem - n * K_;
        if (mm == 0)      Wt_rz[(size_t)n * K_ + k]        = f2b(W_r[(size_t)k * H_ + n]);
        else if (mm == 1) Wt_rz[(size_t)(H_ + n) * K_ + k] = f2b(W_z[(size_t)k * H_ + n]);
        else              Wt_c[(size_t)n * K_ + k]         = f2b(W_c[(size_t)k * H_ + n]);
    }
    if (idx < B_ * H_) { hbuf[idx] = 0.f; hbf16[idx] = 0; }
}

// ---------------------------------------------------------------------------
// GEMM: C(512 x N) = [emb[x[:,t]] | hpart] (512 x 1536) @ Wt^T  (Wt is [N][1536])
// MODE 0: N=2048 (r|z). epilogue: r=sigmoid(.+b_r) -> rh_out=bf16(r*h);
//                                 z=sigmoid(.+b_z) -> zbuf
// MODE 1: N=1024 (candidate). epilogue: ht=tanh(.+b_c);
//                                 h' = (1-z)*h + z*ht -> h_out(fp32), hb_out(bf16)
// ---------------------------------------------------------------------------
template<int MODE>
__global__ __launch_bounds__(256) void gru_gemm(
    const int* __restrict__ x, const float* __restrict__ emb,
    const short* __restrict__ Wt, const short* __restrict__ hpart,
    const float* __restrict__ bias0, const float* __restrict__ bias1,
    const float* __restrict__ hbuf, float* __restrict__ zbuf,
    short* __restrict__ rh_out, float* __restrict__ h_out,
    short* __restrict__ hb_out, int t)
{
    __shared__ short As[64][72];
    __shared__ short Bs[64][72];
    __shared__ int xidx[64];

    const int tid = threadIdx.x;
    const int bm = blockIdx.x, bn = blockIdx.y;

    if (tid < 64) xidx[tid] = x[(bm * 64 + tid) * T_ + t];

    f32x4 acc[2][2] = {};
    const int m  = tid >> 2;          // 0..63 staging row
    const int ks = (tid & 3) * 16;    // 0,16,32,48

    const int w  = tid >> 6, lane = tid & 63;
    const int wm = (w >> 1) * 32, wn = (w & 1) * 32;
    const int lr = lane & 15, lk = (lane >> 4) * 8;

    __syncthreads();  // xidx ready

    for (int kt = 0; kt < 24; ++kt) {
        const int k0 = kt * 64;
        // ---- stage A tile (row m, k0+ks .. +15) ----
        if (k0 < E_) {
            const int row = xidx[m];
            const float4* src = (const float4*)&emb[(size_t)row * E_ + k0 + ks];
            short tmp[16];
            #pragma unroll
            for (int v = 0; v < 4; ++v) {
                float4 f = src[v];
                tmp[v*4+0] = f2b(f.x); tmp[v*4+1] = f2b(f.y);
                tmp[v*4+2] = f2b(f.z); tmp[v*4+3] = f2b(f.w);
            }
            *(s16x8*)&As[m][ks]     = *(const s16x8*)&tmp[0];
            *(s16x8*)&As[m][ks + 8] = *(const s16x8*)&tmp[8];
        } else {
            const s16x8* src = (const s16x8*)&hpart[(size_t)(bm*64 + m) * H_ + (k0 - E_ + ks)];
            *(s16x8*)&As[m][ks]     = src[0];
            *(s16x8*)&As[m][ks + 8] = src[1];
        }
        // ---- stage B tile (Wt row bn*64+m, contiguous k) ----
        {
            const s16x8* src = (const s16x8*)&Wt[(size_t)(bn*64 + m) * K_ + k0 + ks];
            *(s16x8*)&Bs[m][ks]     = src[0];
            *(s16x8*)&Bs[m][ks + 8] = src[1];
        }
        __syncthreads();

        #pragma unroll
        for (int kk = 0; kk < 64; kk += 32) {
            s16x8 a0 = *(const s16x8*)&As[wm      + lr][kk + lk];
            s16x8 a1 = *(const s16x8*)&As[wm + 16 + lr][kk + lk];
            s16x8 b0 = *(const s16x8*)&Bs[wn      + lr][kk + lk];
            s16x8 b1 = *(const s16x8*)&Bs[wn + 16 + lr][kk + lk];
            acc[0][0] = __builtin_amdgcn_mfma_f32_16x16x32_bf16(a0, b0, acc[0][0], 0, 0, 0);
            acc[0][1] = __builtin_amdgcn_mfma_f32_16x16x32_bf16(a0, b1, acc[0][1], 0, 0, 0);
            acc[1][0] = __builtin_amdgcn_mfma_f32_16x16x32_bf16(a1, b0, acc[1][0], 0, 0, 0);
            acc[1][1] = __builtin_amdgcn_mfma_f32_16x16x32_bf16(a1, b1, acc[1][1], 0, 0, 0);
        }
        __syncthreads();
    }

    // ---- epilogue: D row = (lane>>4)*4 + reg, col = lane&15 (within 16x16) ----
    #pragma unroll
    for (int fm = 0; fm < 2; ++fm)
    #pragma unroll
    for (int fn = 0; fn < 2; ++fn)
    #pragma unroll
    for (int r = 0; r < 4; ++r) {
        const int row = bm * 64 + wm + fm * 16 + ((lane >> 4) * 4 + r);
        const int n   = bn * 64 + wn + fn * 16 + (lane & 15);
        float v = acc[fm][fn][r];
        if (MODE == 0) {
            if (n < H_) {
                float rr = sigmoidf_(v + bias0[n]);
                size_t idx = (size_t)row * H_ + n;
                rh_out[idx] = f2b(rr * hbuf[idx]);
            } else {
                int nz = n - H_;
                zbuf[(size_t)row * H_ + nz] = sigmoidf_(v + bias1[nz]);
            }
        } else {
            float ht = tanhf(v + bias0[n]);
            size_t idx = (size_t)row * H_ + n;
            float h = hbuf[idx], z = zbuf[idx];
            float hn = (1.f - z) * h + z * ht;
            h_out[idx]  = hn;
            hb_out[idx] = f2b(hn);
        }
    }
}

// ---------------------------------------------------------------------------
// final FC: out[b] = sigmoid(h[b,:] . W_fc + b_fc), one wave per row
// ---------------------------------------------------------------------------
__global__ __launch_bounds__(256) void fc_kernel(
    const float* __restrict__ h, const float* __restrict__ Wfc,
    const float* __restrict__ bfc, float* __restrict__ out)
{
    int gw   = (blockIdx.x * 256 + threadIdx.x) >> 6;
    int lane = threadIdx.x & 63;
    if (gw >= B_) return;
    float s = 0.f;
    for (int j = lane; j < H_; j += 64) s += h[(size_t)gw * H_ + j] * Wfc[j];
    #pragma unroll
    for (int off = 32; off; off >>= 1) s += __shfl_down(s, off);
    if (lane == 0) out[gw] = sigmoidf_(s + bfc[0]);
}

// ---------------------------------------------------------------------------
extern "C" void kernel_launch(void* const* d_in, const int* in_sizes, int n_in,
                              void* d_out, int out_size, void* d_ws, size_t ws_size,
                              hipStream_t stream) {
    const int*   x    = (const int*)  d_in[0];
    const float* emb  = (const float*)d_in[1];
    const float* W_r  = (const float*)d_in[2];
    const float* b_r  = (const float*)d_in[3];
    const float* W_z  = (const float*)d_in[4];
    const float* b_z  = (const float*)d_in[5];
    const float* W_c  = (const float*)d_in[6];
    const float* b_c  = (const float*)d_in[7];
    const float* W_fc = (const float*)d_in[8];
    const float* b_fc = (const float*)d_in[9];

    char* ws = (char*)d_ws;
    short* Wt_rz  = (short*)(ws);                     // 2048*1536 bf16 = 6291456 B
    short* Wt_c   = (short*)(ws + 6291456);           // 1024*1536 bf16 = 3145728 B
    float* hbuf   = (float*)(ws + 9437184);           // 512*1024 f32   = 2097152 B
    short* hbf16  = (short*)(ws + 11534336);          // 512*1024 bf16  = 1048576 B
    short* rhbf16 = (short*)(ws + 12582912);          // 512*1024 bf16  = 1048576 B
    float* zbuf   = (float*)(ws + 13631488);          // 512*1024 f32   = 2097152 B
    // total 15728640 B

    prep_kernel<<<18432, 256, 0, stream>>>(W_r, W_z, W_c, Wt_rz, Wt_c, hbuf, hbf16);

    for (int t = 0; t < T_; ++t) {
        gru_gemm<0><<<dim3(8, 32), 256, 0, stream>>>(
            x, emb, Wt_rz, hbf16, b_r, b_z, hbuf, zbuf, rhbf16, nullptr, nullptr, t);
        gru_gemm<1><<<dim3(8, 16), 256, 0, stream>>>(
            x, emb, Wt_c, rhbf16, b_c, nullptr, hbuf, zbuf, nullptr, hbuf, hbf16, t);
    }

    fc_kernel<<<128, 256, 0, stream>>>(hbuf, W_fc, b_fc, (float*)d_out);
}